// Round 9
// baseline (306.684 us; speedup 1.0000x reference)
//
#include <hip/hip_runtime.h>

// Dynamic filter layer, 'valid', stride 1:
// out[b,i,j,c] = sum_{di,dj} x[b,i+di,j+dj,c] * flow[b,i,j,di*K+dj]
// B=8, H=W=256, C=64, K=5, Ho=Wo=252. All fp32.
//
// R10: zero-LDS restructure. R9 (90us) hit the LDS roofline: K=5x read
// amplification on x + 16x q-amplification on flow = 2.5 GB LDS traffic
// (>=32us) + 5.5M bank conflicts, with occupancy still 28%.
// New mapping: ONE WAVE per (j-pair, 12-row segment); LANE = CHANNEL (C=64).
//  - flow indices wave-uniform (j from readfirstlane(wave-id)) -> compiler
//    lowers flow reads to s_load into SGPRs; FMA = v_fmac v,s,v. Flow moves
//    to the idle SMEM/K$ pipe: no LDS, no VGPR cost, 16x amp gone.
//  - x: lane-coalesced b32 (64ch x 4B = 256B/instr), 7-row x 6-px register
//    ring, all indices compile-time (full unroll). J=2 adjacent cols/wave:
//    6 px/row per 2 outputs (3 loads/output vs 5).
//  - No LDS, no barriers, no bounds guards: edge j-blocks clamp j0 to 250
//    and redundantly recompute identical values (duplicate identical NT
//    stores are benign).
// Latency hiding via TLP: ~55-65 VGPR -> 6-8 waves/SIMD (~3x R9).
// Design signature to verify in counters: LDS_Block_Size=0, BANK_CONFLICT~0.

constexpr int B  = 8;
constexpr int H  = 256;
constexpr int W  = 256;
constexpr int C  = 64;
constexpr int K  = 5;
constexpr int Ho = H - K + 1;            // 252
constexpr int Wo = W - K + 1;            // 252
constexpr int R  = 12;                   // output rows per wave (Ho % R == 0)
constexpr int SEG = Ho / R;              // 21 row segments
constexpr int NR  = R + K - 1;           // 16 x rows per wave
constexpr int J   = 2;                   // output cols per wave
constexpr int PXW = K - 1 + J;           // 6 x pixels per row window
constexpr int WPB = 4;                   // waves per block (256 threads)
constexpr int JBLK = (Wo + WPB*J - 1) / (WPB*J);  // 32 j-blocks (last clamped)
constexpr int RING = 7;                  // x row ring: 5 live + 2 prefetch

__global__ void dfl_kernel(const float* __restrict__ x,
                           const float* __restrict__ flow,
                           float* __restrict__ out)
{
    const int t = threadIdx.x;
    const int c = t & 63;                                  // lane = channel
    const int wv = __builtin_amdgcn_readfirstlane(t >> 6); // uniform wave id

    int bid = blockIdx.x;
    const int jb  = bid % JBLK; bid /= JBLK;
    const int seg = bid % SEG;  bid /= SEG;
    const int b   = bid;

    int j0 = jb * (WPB * J) + wv * J;                      // uniform
    if (j0 > Wo - J) j0 = Wo - J;       // edge clamp: duplicate compute, benign
    const int i0 = seg * R;

    // x/out: uniform base + lane channel offset. x loads: 64x4B coalesced.
    const float* xb = x   + (((size_t)(b * H  + i0) * W  + j0) << 6) + c;
    float*       ob = out + (((size_t)(b * Ho + i0) * Wo + j0) << 6) + c;
    // flow: fully wave-uniform address -> scalar loads (SGPR weights).
    const float* fb = flow + (size_t)((b * Ho + i0) * Wo + j0) * (K * K);

    float xw[RING][PXW];                 // 42 VGPR register ring, static idx

    // ---- prologue: rows 0..5 (covers ii=0 taps + 1 prefetched) ----
    #pragma unroll
    for (int r = 0; r < K + 1; ++r)
        #pragma unroll
        for (int p = 0; p < PXW; ++p)
            xw[r % RING][p] = xb[(size_t)r * (W * C) + p * C];

    // ---- steady state: prefetch row ii+6 (used at step ii+2), compute ii ----
    #pragma unroll
    for (int ii = 0; ii < R; ++ii) {
        const int rr = ii + K + 1;
        if (rr < NR) {                   // compile-time resolved
            #pragma unroll
            for (int p = 0; p < PXW; ++p)
                xw[rr % RING][p] = xb[(size_t)rr * (W * C) + p * C];
        }
        #pragma unroll
        for (int jx = 0; jx < J; ++jx) {
            const float* fw = fb + (size_t)ii * (Wo * K * K) + jx * (K * K);
            float acc = 0.f;
            #pragma unroll
            for (int di = 0; di < K; ++di)
                #pragma unroll
                for (int dj = 0; dj < K; ++dj)
                    acc += xw[(ii + di) % RING][dj + jx] * fw[di * K + dj];
            __builtin_nontemporal_store(acc, ob + (size_t)ii * (Wo * C) + jx * C);
        }
    }
}

extern "C" void kernel_launch(void* const* d_in, const int* in_sizes, int n_in,
                              void* d_out, int out_size, void* d_ws, size_t ws_size,
                              hipStream_t stream) {
    const float* x    = (const float*)d_in[0];
    const float* flow = (const float*)d_in[1];
    // d_in[2] is ksize (scalar), fixed at 5 — baked in as constexpr.
    float* out = (float*)d_out;

    const int grid = B * SEG * JBLK;      // 8 * 21 * 32 = 5376 blocks
    dfl_kernel<<<grid, 256, 0, stream>>>(x, flow, out);
}